// Round 5
// baseline (345.662 us; speedup 1.0000x reference)
//
#include <hip/hip_runtime.h>
#include <hip/hip_bf16.h>
#include <math.h>

#define NROWS 8192
#define DDIM  10000
#define NCLS  100
#define LISTCAP 512

#define KSPLIT 8
#define KSTEPS 157            // ceil(10000/64)
#define BM 64
#define BK 64

#define SCORES_N (NROWS*NCLS)
#define NCHUNK8 1256          // k-octets, padded to 10048
#define BP_CHUNKS (NCHUNK8*128)

// ws layout in float (4B) units
#define WS_NORMCLS 0                                   // 128
#define WS_NRM     128                                 // KSPLIT*NROWS
#define WS_SCP     (WS_NRM + KSPLIT*NROWS)             // KSPLIT*NROWS*NCLS
#define WS_CNT_T   (WS_SCP + KSPLIT*SCORES_N)          // 128
#define WS_CNT_P   (WS_CNT_T + 128)                    // 128
#define WS_LIST_T  (WS_CNT_P + 128)                    // NCLS*LISTCAP
#define WS_LIST_P  (WS_LIST_T + NCLS*LISTCAP)          // NCLS*LISTCAP
#define WS_BPH     (WS_LIST_P + NCLS*LISTCAP)          // BP_CHUNKS*4 floats (8 f16 each)
#define WS_BPL     (WS_BPH + BP_CHUNKS*4)

typedef _Float16 f16;
typedef f16 f16x8 __attribute__((ext_vector_type(8)));
typedef float f32x4 __attribute__((ext_vector_type(4)));

#define SBAR()  __builtin_amdgcn_s_barrier()
#define SCHED() __builtin_amdgcn_sched_barrier(0)

// ---------------- Phase 0: class norms (+ zero list counters) ----------------
__global__ __launch_bounds__(256) void cls_norms(const float* __restrict__ cls,
                                                 float* __restrict__ ws)
{
    if (blockIdx.x == 0) ((int*)ws)[WS_CNT_T + threadIdx.x] = 0;  // 256 ints: CNT_T + CNT_P

    int c = blockIdx.x;
    const float* row = cls + (size_t)c * DDIM;
    float s = 0.f;
    for (int d = threadIdx.x; d < DDIM; d += 256) {
        float v = row[d];
        s = fmaf(v, v, s);
    }
    #pragma unroll
    for (int off = 32; off; off >>= 1) s += __shfl_xor(s, off, 64);
    __shared__ float red[4];
    int w = threadIdx.x >> 6, l = threadIdx.x & 63;
    if (l == 0) red[w] = s;
    __syncthreads();
    if (threadIdx.x == 0) {
        float t = red[0] + red[1] + red[2] + red[3];
        ws[WS_NORMCLS + c] = sqrtf(t);
    }
}

// ---------------- Phase 0b: class_hvs -> fp16 hi/lo, chunked [k8][col][8] ----------------
__global__ __launch_bounds__(256) void prep_b(const float* __restrict__ cls,
                                              float* __restrict__ ws)
{
    int c = blockIdx.x * 256 + threadIdx.x;
    if (c >= BP_CHUNKS) return;
    int col = c & 127, k8 = c >> 7;
    f16x8 hi, lo;
    #pragma unroll
    for (int j = 0; j < 8; ++j) {
        int k = k8 * 8 + j;
        float v = (col < NCLS && k < DDIM) ? cls[(size_t)col * DDIM + k] : 0.f;
        f16 h = (f16)v;
        hi[j] = h;
        lo[j] = (f16)(v - (float)h);
    }
    ((f16x8*)(ws + WS_BPH))[c] = hi;
    ((f16x8*)(ws + WS_BPL))[c] = lo;
}

// ---------------- Phase 1: MFMA GEMM, fp16 split; A dbuf LDS, B from L2 regs ----------------
// grid (128, KSPLIT); 4 waves; wave w -> cols [32w, 32w+32)
// per iter: 1 barrier; A reg-prefetch depth 2; B loaded at iter top.
__global__ __launch_bounds__(256, 4) void gemm_mfma(const float* __restrict__ enc,
                                                    float* __restrict__ ws)
{
    __shared__ f16 Ah[2][8*64*8], Al[2][8*64*8];   // [buf][kg 0..7][row^kg][8]

    int tid = threadIdx.x;
    int w = __builtin_amdgcn_readfirstlane(tid >> 6);
    int l = tid & 63;
    int lane15 = l & 15, lg = l >> 4;
    int row_a = tid >> 2, q = tid & 3;        // A staging: thread = (row, k-quarter)
    int r0 = blockIdx.x * BM;
    int ky = blockIdx.y;
    int s_beg = (KSTEPS * ky) / KSPLIT;
    int s_end = (KSTEPS * (ky + 1)) / KSPLIT;

    const float* aptr = enc + (size_t)(r0 + row_a) * DDIM;
    const f16* bph = (const f16*)(ws + WS_BPH);
    const f16* bpl = (const f16*)(ws + WS_BPL);

    f32x4 acc[4][2] = {};
    float nsq = 0.f;
    float4 ar0[4], ar1[4];                    // depth-2 A prefetch slots

    #define ISSUE_A(S, AR) do {                                         \
        int kb_ = (S) * BK + q * 16;                                    \
        _Pragma("unroll")                                               \
        for (int i_ = 0; i_ < 4; ++i_) {                                \
            int k_ = kb_ + 4 * i_;                                      \
            (AR)[i_] = *(const float4*)(aptr + ((k_ + 4 <= DDIM) ? k_ : 0)); \
        }                                                               \
    } while (0)

    ISSUE_A(s_beg, ar0);
    ISSUE_A(s_beg + 1, ar1);

    int nsteps = s_end - s_beg;

    #define BODY(T, AR, BUF) do {                                       \
        int s = s_beg + (T);                                            \
        /* 1. convert A(s) (masked on global tail) */                   \
        bool tail = (s == KSTEPS - 1);                                  \
        int kmax = DDIM - (s * BK + q * 16);                            \
        f16x8 hv[2], lv[2];                                             \
        _Pragma("unroll")                                               \
        for (int jj = 0; jj < 2; ++jj) {                                \
            float4 a0 = (AR)[2 * jj], a1 = (AR)[2 * jj + 1];            \
            float v[8] = {a0.x, a0.y, a0.z, a0.w, a1.x, a1.y, a1.z, a1.w}; \
            if (tail) {                                                 \
                _Pragma("unroll")                                       \
                for (int j = 0; j < 8; ++j) v[j] = (jj * 8 + j < kmax) ? v[j] : 0.f; \
            }                                                           \
            _Pragma("unroll")                                           \
            for (int j = 0; j < 8; ++j) {                               \
                f16 h = (f16)v[j];                                      \
                hv[jj][j] = h;                                          \
                lv[jj][j] = (f16)(v[j] - (float)h);                     \
                nsq = fmaf(v[j], v[j], nsq);                            \
            }                                                           \
        }                                                               \
        /* 2. ds_write A(s) -> buf (XOR-swizzled rows) */               \
        _Pragma("unroll")                                               \
        for (int jj = 0; jj < 2; ++jj) {                                \
            int kg = 2 * q + jj;                                        \
            int off = kg * 512 + (row_a ^ kg) * 8;                      \
            *(f16x8*)&Ah[BUF][off] = hv[jj];                            \
            *(f16x8*)&Al[BUF][off] = lv[jj];                            \
        }                                                               \
        /* 3. issue A(s+2) into the slot just freed */                  \
        ISSUE_A(s + 2, AR);                                             \
        /* 4. issue B(s) register loads (L2-resident) */                \
        f16x8 bh_[2][2], bl_[2][2];                                     \
        _Pragma("unroll")                                               \
        for (int kf = 0; kf < 2; ++kf) {                                \
            int kg = kf * 4 + lg;                                       \
            size_t kb = ((size_t)(s * 8 + kg)) * 128;                   \
            _Pragma("unroll")                                           \
            for (int nt = 0; nt < 2; ++nt) {                            \
                int col = w * 32 + nt * 16 + lane15;                    \
                bh_[kf][nt] = *(const f16x8*)(bph + (kb + col) * 8);    \
                bl_[kf][nt] = *(const f16x8*)(bpl + (kb + col) * 8);    \
            }                                                           \
        }                                                               \
        /* 5. fence: ds_writes visible, all waves arrived */            \
        SCHED();                                                        \
        asm volatile("s_waitcnt lgkmcnt(0)" ::: "memory");              \
        SBAR();                                                         \
        SCHED();                                                        \
        /* 6. MFMA: ds_read A frags + 48 MFMA */                        \
        _Pragma("unroll")                                               \
        for (int kf = 0; kf < 2; ++kf) {                                \
            int kg = kf * 4 + lg;                                       \
            _Pragma("unroll")                                           \
            for (int mt = 0; mt < 4; ++mt) {                            \
                int ro = (mt * 16 + lane15) ^ kg;                       \
                f16x8 ah = *(const f16x8*)&Ah[BUF][kg * 512 + ro * 8];  \
                f16x8 al = *(const f16x8*)&Al[BUF][kg * 512 + ro * 8];  \
                acc[mt][0] = __builtin_amdgcn_mfma_f32_16x16x32_f16(ah, bh_[kf][0], acc[mt][0], 0, 0, 0); \
                acc[mt][1] = __builtin_amdgcn_mfma_f32_16x16x32_f16(ah, bh_[kf][1], acc[mt][1], 0, 0, 0); \
                acc[mt][0] = __builtin_amdgcn_mfma_f32_16x16x32_f16(al, bh_[kf][0], acc[mt][0], 0, 0, 0); \
                acc[mt][1] = __builtin_amdgcn_mfma_f32_16x16x32_f16(al, bh_[kf][1], acc[mt][1], 0, 0, 0); \
                acc[mt][0] = __builtin_amdgcn_mfma_f32_16x16x32_f16(ah, bl_[kf][0], acc[mt][0], 0, 0, 0); \
                acc[mt][1] = __builtin_amdgcn_mfma_f32_16x16x32_f16(ah, bl_[kf][1], acc[mt][1], 0, 0, 0); \
            }                                                           \
        }                                                               \
    } while (0)

    for (int t = 0; t < nsteps; t += 2) {
        BODY(t, ar0, 0);
        if (t + 1 < nsteps) BODY(t + 1, ar1, 1);
    }

    // ---- epilogue: partial scores ----
    float* scp = ws + WS_SCP + (size_t)ky * SCORES_N;
    #pragma unroll
    for (int mt = 0; mt < 4; ++mt) {
        #pragma unroll
        for (int nt = 0; nt < 2; ++nt) {
            int gcol = w * 32 + nt * 16 + lane15;
            if (gcol < NCLS) {
                #pragma unroll
                for (int j = 0; j < 4; ++j) {
                    int grow = r0 + mt * 16 + lg * 4 + j;
                    scp[(size_t)grow * NCLS + gcol] = acc[mt][nt][j];
                }
            }
        }
    }

    // ---- row-norm partials: reduce across the 4 k-quarter threads of each row ----
    float tn = nsq;
    tn += __shfl_xor(tn, 1, 4);
    tn += __shfl_xor(tn, 2, 4);
    if (q == 0) ws[WS_NRM + (size_t)ky * NROWS + r0 + row_a] = tn;
}

// ---------------- Phase 2: finalize scores, argmax, build class lists ----------------
__global__ __launch_bounds__(256) void finalize(const int* __restrict__ targets,
                                                float* __restrict__ out,
                                                float* __restrict__ ws)
{
    int w = threadIdx.x >> 6, l = threadIdx.x & 63;
    int row = blockIdx.x * 4 + w;
    const float* scp = ws + WS_SCP;

    float n2 = 0.f;
    #pragma unroll
    for (int ky = 0; ky < KSPLIT; ++ky) n2 += ws[WS_NRM + (size_t)ky * NROWS + row];
    float ne = sqrtf(n2);

    float best; int bi;
    {
        int c = l;
        float dsum = 0.f;
        #pragma unroll
        for (int ky = 0; ky < KSPLIT; ++ky)
            dsum += scp[(size_t)ky * SCORES_N + (size_t)row * NCLS + c];
        float s = dsum / (ne * ws[WS_NORMCLS + c]);
        out[(size_t)row * NCLS + c] = s;
        best = s; bi = c;
    }
    if (l + 64 < NCLS) {
        int c = l + 64;
        float dsum = 0.f;
        #pragma unroll
        for (int ky = 0; ky < KSPLIT; ++ky)
            dsum += scp[(size_t)ky * SCORES_N + (size_t)row * NCLS + c];
        float s = dsum / (ne * ws[WS_NORMCLS + c]);
        out[(size_t)row * NCLS + c] = s;
        if (s > best) { best = s; bi = c; }   // ties keep smaller index
    }
    #pragma unroll
    for (int off = 32; off; off >>= 1) {
        float ov = __shfl_xor(best, off, 64);
        int   oi = __shfl_xor(bi, off, 64);
        if (ov > best || (ov == best && oi < bi)) { best = ov; bi = oi; }
    }
    if (l == 0) {
        int tgt = targets[row];
        if (tgt != bi) {
            int* wsi = (int*)ws;
            int p1 = atomicAdd(wsi + WS_CNT_T + tgt, 1);
            if (p1 < LISTCAP) wsi[WS_LIST_T + tgt * LISTCAP + p1] = row;
            int p2 = atomicAdd(wsi + WS_CNT_P + bi, 1);
            if (p2 < LISTCAP) wsi[WS_LIST_P + bi * LISTCAP + p2] = row;
        }
    }
}

// ---------------- Phase 3: perceptron update ----------------
// grid (NCLS, dchunks): class is the FAST dim so a same-d-chunk cohort of 100
// blocks co-runs; each wrong row is read by exactly 2 of them -> L3 absorbs.
__global__ __launch_bounds__(256) void update(const float* __restrict__ enc,
                                              const float* __restrict__ cls,
                                              float* __restrict__ out,
                                              const float* __restrict__ ws)
{
    int c = blockIdx.x;
    int d = blockIdx.y * 256 + threadIdx.x;
    if (d >= DDIM) return;
    const int* wsi = (const int*)ws;

    float acc = 0.f;
    int nt = wsi[WS_CNT_T + c]; nt = nt < LISTCAP ? nt : LISTCAP;
    for (int i = 0; i < nt; ++i) {
        int n = wsi[WS_LIST_T + c * LISTCAP + i];
        acc += enc[(size_t)n * DDIM + d];
    }
    int np = wsi[WS_CNT_P + c]; np = np < LISTCAP ? np : LISTCAP;
    for (int i = 0; i < np; ++i) {
        int n = wsi[WS_LIST_P + c * LISTCAP + i];
        acc -= enc[(size_t)n * DDIM + d];
    }
    out[SCORES_N + (size_t)c * DDIM + d] = cls[(size_t)c * DDIM + d] + acc;
}

// ---------------- launch ----------------
extern "C" void kernel_launch(void* const* d_in, const int* in_sizes, int n_in,
                              void* d_out, int out_size, void* d_ws, size_t ws_size,
                              hipStream_t stream)
{
    const float* enc = (const float*)d_in[0];
    const float* cls = (const float*)d_in[1];
    const int*   tgt = (const int*)d_in[2];
    float* out = (float*)d_out;
    float* ws  = (float*)d_ws;

    cls_norms<<<NCLS, 256, 0, stream>>>(cls, ws);
    prep_b<<<(BP_CHUNKS + 255) / 256, 256, 0, stream>>>(cls, ws);

    dim3 g1(NROWS / BM, KSPLIT);
    gemm_mfma<<<g1, 256, 0, stream>>>(enc, ws);

    finalize<<<NROWS / 4, 256, 0, stream>>>(tgt, out, ws);

    dim3 g3(NCLS, (DDIM + 255) / 256);
    update<<<g3, 256, 0, stream>>>(enc, cls, out, ws);
}

// Round 6
// 271.752 us; speedup vs baseline: 1.2720x; 1.2720x over previous
//
#include <hip/hip_runtime.h>
#include <hip/hip_bf16.h>
#include <math.h>

#define NROWS 8192
#define DDIM  10000
#define NCLS  100
#define LISTCAP 512

#define KSPLIT 8
#define KS32   314            // ceil(10048/32) k32-steps total
#define BM 64

#define SCORES_N (NROWS*NCLS)
#define NCHUNK8 1256          // k-octets, padded to 10048
#define BP_CHUNKS (NCHUNK8*128)

// ws layout in float (4B) units
#define WS_NORMCLS 0                                   // 128
#define WS_NRM     128                                 // KSPLIT*NROWS
#define WS_SCP     (WS_NRM + KSPLIT*NROWS)             // KSPLIT*NROWS*NCLS
#define WS_CNT_T   (WS_SCP + KSPLIT*SCORES_N)          // 128
#define WS_CNT_P   (WS_CNT_T + 128)                    // 128
#define WS_LIST_T  (WS_CNT_P + 128)                    // NCLS*LISTCAP
#define WS_LIST_P  (WS_LIST_T + NCLS*LISTCAP)          // NCLS*LISTCAP
#define WS_BPH     (WS_LIST_P + NCLS*LISTCAP)          // BP_CHUNKS*4 floats (8 f16 each)
#define WS_BPL     (WS_BPH + BP_CHUNKS*4)

typedef _Float16 f16;
typedef f16 f16x8 __attribute__((ext_vector_type(8)));
typedef float f32x4 __attribute__((ext_vector_type(4)));

#define SBAR()  __builtin_amdgcn_s_barrier()
#define SCHED() __builtin_amdgcn_sched_barrier(0)

// ---------------- Phase 0: class norms (+ zero list counters) ----------------
__global__ __launch_bounds__(256) void cls_norms(const float* __restrict__ cls,
                                                 float* __restrict__ ws)
{
    if (blockIdx.x == 0) ((int*)ws)[WS_CNT_T + threadIdx.x] = 0;  // 256 ints: CNT_T + CNT_P

    int c = blockIdx.x;
    const float* row = cls + (size_t)c * DDIM;
    float s = 0.f;
    for (int d = threadIdx.x; d < DDIM; d += 256) {
        float v = row[d];
        s = fmaf(v, v, s);
    }
    #pragma unroll
    for (int off = 32; off; off >>= 1) s += __shfl_xor(s, off, 64);
    __shared__ float red[4];
    int w = threadIdx.x >> 6, l = threadIdx.x & 63;
    if (l == 0) red[w] = s;
    __syncthreads();
    if (threadIdx.x == 0) {
        float t = red[0] + red[1] + red[2] + red[3];
        ws[WS_NORMCLS + c] = sqrtf(t);
    }
}

// ---------------- Phase 0b: class_hvs -> fp16 hi/lo, chunked [k8][col][8] ----------------
__global__ __launch_bounds__(256) void prep_b(const float* __restrict__ cls,
                                              float* __restrict__ ws)
{
    int c = blockIdx.x * 256 + threadIdx.x;
    if (c >= BP_CHUNKS) return;
    int col = c & 127, k8 = c >> 7;
    f16x8 hi, lo;
    #pragma unroll
    for (int j = 0; j < 8; ++j) {
        int k = k8 * 8 + j;
        float v = (col < NCLS && k < DDIM) ? cls[(size_t)col * DDIM + k] : 0.f;
        f16 h = (f16)v;
        hi[j] = h;
        lo[j] = (f16)(v - (float)h);
    }
    ((f16x8*)(ws + WS_BPH))[c] = hi;
    ((f16x8*)(ws + WS_BPL))[c] = lo;
}

// ---------------- Phase 1: MFMA GEMM ----------------
// A: HBM -> per-lane frag regs -> convert (NO LDS). B: prepped hi/lo, regs -> LDS dbuf.
// grid (128, KSPLIT); 4 waves; wave w -> rows [r0+16w, +16), all 112 live cols.
__global__ __launch_bounds__(256, 4) void gemm_mfma(const float* __restrict__ enc,
                                                    float* __restrict__ ws)
{
    __shared__ f16 Bh[2][4*128*8], Bl[2][4*128*8];   // [buf][kg][colS][8], 8KB halves

    int tid = threadIdx.x;
    int w = __builtin_amdgcn_readfirstlane(tid >> 6);
    int l = tid & 63;
    int lane15 = l & 15, lg = l >> 4;
    int r0 = blockIdx.x * BM;
    int ky = blockIdx.y;
    int s_beg = (KS32 * ky) / KSPLIT;
    int s_end = (KS32 * (ky + 1)) / KSPLIT;

    const float* aptr = enc + (size_t)(r0 + w * 16 + lane15) * DDIM;
    const f16* bph = (const f16*)(ws + WS_BPH);
    const f16* bpl = (const f16*)(ws + WS_BPL);

    f32x4 acc[7] = {};
    float nsq = 0.f;

    float4 a0, a1;                 // A(S) frag f32 (8 elems: k = S*32 + lg*8 + j)
    f16x8 bsh0, bsh1, bsl0, bsl1;  // B(S) stage regs (wave's kg=w share)

    #define LOAD_A(S) do {                                              \
        int k_ = (S) * 32 + lg * 8;                                     \
        a0 = *(const float4*)(aptr + ((k_ + 4 <= DDIM) ? k_ : 0));      \
        a1 = *(const float4*)(aptr + ((k_ + 8 <= DDIM) ? (k_ + 4) : 0)); \
    } while (0)

    #define LOAD_B(S) do {                                              \
        size_t base_ = ((size_t)((S) * 4 + w) * 128) * 8;               \
        bsh0 = *(const f16x8*)(bph + base_ + (size_t)l * 8);            \
        bsh1 = *(const f16x8*)(bph + base_ + (size_t)(l + 64) * 8);     \
        bsl0 = *(const f16x8*)(bpl + base_ + (size_t)l * 8);            \
        bsl1 = *(const f16x8*)(bpl + base_ + (size_t)(l + 64) * 8);     \
    } while (0)

    LOAD_A(s_beg);
    LOAD_B(s_beg);

    for (int S = s_beg; S < s_end; ++S) {
        int cur = S & 1;

        // 1. convert A(S) regs -> hi/lo frags (+ tail mask + norm accum)
        float v[8] = {a0.x, a0.y, a0.z, a0.w, a1.x, a1.y, a1.z, a1.w};
        int kb = S * 32 + lg * 8;
        if (kb + 8 > DDIM) {
            #pragma unroll
            for (int j = 0; j < 8; ++j) if (kb + j >= DDIM) v[j] = 0.f;
        }
        f16x8 ah, al;
        #pragma unroll
        for (int j = 0; j < 8; ++j) {
            f16 h = (f16)v[j];
            ah[j] = h;
            al[j] = (f16)(v[j] - (float)h);
            nsq = fmaf(v[j], v[j], nsq);
        }

        // 2. ds_write B(S) stage regs -> buf[cur], XOR-swizzled slots
        {
            int sl0 = w * 128 + (l ^ w);
            *(f16x8*)&Bh[cur][sl0 * 8] = bsh0;
            *(f16x8*)&Bh[cur][(sl0 + 64) * 8] = bsh1;
            *(f16x8*)&Bl[cur][sl0 * 8] = bsl0;
            *(f16x8*)&Bl[cur][(sl0 + 64) * 8] = bsl1;
        }

        // 3. prefetch A(S+1), B(S+1) (clamped reload at the end, discarded)
        {
            int Sn = (S + 1 < s_end) ? (S + 1) : S;
            LOAD_A(Sn);
            LOAD_B(Sn);
        }

        // 4. fence: B(S) ds_writes visible to all waves
        SCHED();
        asm volatile("s_waitcnt lgkmcnt(0)" ::: "memory");
        SBAR();
        SCHED();

        // 5. read B frags + 21 MFMA (cols 0..111; nt=7 is padding, skipped)
        #pragma unroll
        for (int nt = 0; nt < 7; ++nt) {
            int colS = (nt * 16 + lane15) ^ lg;
            f16x8 bh = *(const f16x8*)&Bh[cur][(lg * 128 + colS) * 8];
            f16x8 bl = *(const f16x8*)&Bl[cur][(lg * 128 + colS) * 8];
            acc[nt] = __builtin_amdgcn_mfma_f32_16x16x32_f16(ah, bh, acc[nt], 0, 0, 0);
            acc[nt] = __builtin_amdgcn_mfma_f32_16x16x32_f16(al, bh, acc[nt], 0, 0, 0);
            acc[nt] = __builtin_amdgcn_mfma_f32_16x16x32_f16(ah, bl, acc[nt], 0, 0, 0);
        }
    }

    // ---- epilogue: partial scores (C layout: col=lane15, row=lg*4+j) ----
    float* scp = ws + WS_SCP + (size_t)ky * SCORES_N;
    #pragma unroll
    for (int nt = 0; nt < 7; ++nt) {
        int gcol = nt * 16 + lane15;
        if (gcol < NCLS) {
            #pragma unroll
            for (int j = 0; j < 4; ++j) {
                int grow = r0 + w * 16 + lg * 4 + j;
                scp[(size_t)grow * NCLS + gcol] = acc[nt][j];
            }
        }
    }

    // ---- row-norm partials: reduce across lg (lanes l, l+16, l+32, l+48) ----
    float tn = nsq;
    tn += __shfl_xor(tn, 16, 64);
    tn += __shfl_xor(tn, 32, 64);
    if (l < 16) ws[WS_NRM + (size_t)ky * NROWS + r0 + w * 16 + l] = tn;
}

// ---------------- Phase 2: finalize scores, argmax, build class lists ----------------
__global__ __launch_bounds__(256) void finalize(const int* __restrict__ targets,
                                                float* __restrict__ out,
                                                float* __restrict__ ws)
{
    int w = threadIdx.x >> 6, l = threadIdx.x & 63;
    int row = blockIdx.x * 4 + w;
    const float* scp = ws + WS_SCP;

    float n2 = 0.f;
    #pragma unroll
    for (int ky = 0; ky < KSPLIT; ++ky) n2 += ws[WS_NRM + (size_t)ky * NROWS + row];
    float ne = sqrtf(n2);

    float best; int bi;
    {
        int c = l;
        float dsum = 0.f;
        #pragma unroll
        for (int ky = 0; ky < KSPLIT; ++ky)
            dsum += scp[(size_t)ky * SCORES_N + (size_t)row * NCLS + c];
        float s = dsum / (ne * ws[WS_NORMCLS + c]);
        out[(size_t)row * NCLS + c] = s;
        best = s; bi = c;
    }
    if (l + 64 < NCLS) {
        int c = l + 64;
        float dsum = 0.f;
        #pragma unroll
        for (int ky = 0; ky < KSPLIT; ++ky)
            dsum += scp[(size_t)ky * SCORES_N + (size_t)row * NCLS + c];
        float s = dsum / (ne * ws[WS_NORMCLS + c]);
        out[(size_t)row * NCLS + c] = s;
        if (s > best) { best = s; bi = c; }   // ties keep smaller index
    }
    #pragma unroll
    for (int off = 32; off; off >>= 1) {
        float ov = __shfl_xor(best, off, 64);
        int   oi = __shfl_xor(bi, off, 64);
        if (ov > best || (ov == best && oi < bi)) { best = ov; bi = oi; }
    }
    if (l == 0) {
        int tgt = targets[row];
        if (tgt != bi) {
            int* wsi = (int*)ws;
            int p1 = atomicAdd(wsi + WS_CNT_T + tgt, 1);
            if (p1 < LISTCAP) wsi[WS_LIST_T + tgt * LISTCAP + p1] = row;
            int p2 = atomicAdd(wsi + WS_CNT_P + bi, 1);
            if (p2 < LISTCAP) wsi[WS_LIST_P + bi * LISTCAP + p2] = row;
        }
    }
}

// ---------------- Phase 3: perceptron update (float4, class-fast cohort) ----------------
__global__ __launch_bounds__(256) void update(const float* __restrict__ enc,
                                              const float* __restrict__ cls,
                                              float* __restrict__ out,
                                              const float* __restrict__ ws)
{
    int c = blockIdx.x;
    int d4 = blockIdx.y * 256 + threadIdx.x;     // float4 index; DDIM/4 = 2500
    if (d4 >= DDIM / 4) return;
    const int* wsi = (const int*)ws;
    const float4* enc4 = (const float4*)enc;
    const float4* cls4 = (const float4*)cls;

    float4 acc = make_float4(0.f, 0.f, 0.f, 0.f);
    int nt = wsi[WS_CNT_T + c]; nt = nt < LISTCAP ? nt : LISTCAP;
    for (int i = 0; i < nt; ++i) {
        int n = wsi[WS_LIST_T + c * LISTCAP + i];
        float4 e = enc4[(size_t)n * (DDIM / 4) + d4];
        acc.x += e.x; acc.y += e.y; acc.z += e.z; acc.w += e.w;
    }
    int np = wsi[WS_CNT_P + c]; np = np < LISTCAP ? np : LISTCAP;
    for (int i = 0; i < np; ++i) {
        int n = wsi[WS_LIST_P + c * LISTCAP + i];
        float4 e = enc4[(size_t)n * (DDIM / 4) + d4];
        acc.x -= e.x; acc.y -= e.y; acc.z -= e.z; acc.w -= e.w;
    }
    float4 cv = cls4[(size_t)c * (DDIM / 4) + d4];
    float4 r = make_float4(cv.x + acc.x, cv.y + acc.y, cv.z + acc.z, cv.w + acc.w);
    ((float4*)out)[SCORES_N / 4 + (size_t)c * (DDIM / 4) + d4] = r;
}

// ---------------- launch ----------------
extern "C" void kernel_launch(void* const* d_in, const int* in_sizes, int n_in,
                              void* d_out, int out_size, void* d_ws, size_t ws_size,
                              hipStream_t stream)
{
    const float* enc = (const float*)d_in[0];
    const float* cls = (const float*)d_in[1];
    const int*   tgt = (const int*)d_in[2];
    float* out = (float*)d_out;
    float* ws  = (float*)d_ws;

    cls_norms<<<NCLS, 256, 0, stream>>>(cls, ws);
    prep_b<<<(BP_CHUNKS + 255) / 256, 256, 0, stream>>>(cls, ws);

    dim3 g1(NROWS / BM, KSPLIT);
    gemm_mfma<<<g1, 256, 0, stream>>>(enc, ws);

    finalize<<<NROWS / 4, 256, 0, stream>>>(tgt, out, ws);

    dim3 g3(NCLS, (DDIM / 4 + 255) / 256);
    update<<<g3, 256, 0, stream>>>(enc, cls, out, ws);
}

// Round 7
// 242.566 us; speedup vs baseline: 1.4250x; 1.1203x over previous
//
#include <hip/hip_runtime.h>
#include <hip/hip_bf16.h>
#include <math.h>

#define NROWS 8192
#define DDIM  10000
#define NCLS  100
#define LISTCAP 512

#define KSPLIT 8
#define KS32   314            // ceil(10048/32) k32-steps total
#define BM 128

#define SCORES_N (NROWS*NCLS)
#define NCHUNK8 1256          // k-octets, padded to 10048
#define BP_CHUNKS (NCHUNK8*128)

// ws layout in float (4B) units
#define WS_NORMCLS 0                                   // 128
#define WS_NRM     128                                 // KSPLIT*NROWS
#define WS_SCP     (WS_NRM + KSPLIT*NROWS)             // KSPLIT*NROWS*NCLS
#define WS_CNT_T   (WS_SCP + KSPLIT*SCORES_N)          // 128
#define WS_CNT_P   (WS_CNT_T + 128)                    // 128
#define WS_LIST_T  (WS_CNT_P + 128)                    // NCLS*LISTCAP
#define WS_LIST_P  (WS_LIST_T + NCLS*LISTCAP)          // NCLS*LISTCAP
#define WS_BPH     (WS_LIST_P + NCLS*LISTCAP)          // BP_CHUNKS*4 floats (8 f16 each)
#define WS_BPL     (WS_BPH + BP_CHUNKS*4)

typedef _Float16 f16;
typedef f16 f16x8 __attribute__((ext_vector_type(8)));
typedef float f32x4 __attribute__((ext_vector_type(4)));

#define SBAR()  __builtin_amdgcn_s_barrier()
#define SCHED() __builtin_amdgcn_sched_barrier(0)

// ---------------- Phase 0: class norms (+ zero list counters) ----------------
__global__ __launch_bounds__(256) void cls_norms(const float* __restrict__ cls,
                                                 float* __restrict__ ws)
{
    if (blockIdx.x == 0) ((int*)ws)[WS_CNT_T + threadIdx.x] = 0;  // 256 ints: CNT_T + CNT_P

    int c = blockIdx.x;
    const float* row = cls + (size_t)c * DDIM;
    float s = 0.f;
    for (int d = threadIdx.x; d < DDIM; d += 256) {
        float v = row[d];
        s = fmaf(v, v, s);
    }
    #pragma unroll
    for (int off = 32; off; off >>= 1) s += __shfl_xor(s, off, 64);
    __shared__ float red[4];
    int w = threadIdx.x >> 6, l = threadIdx.x & 63;
    if (l == 0) red[w] = s;
    __syncthreads();
    if (threadIdx.x == 0) {
        float t = red[0] + red[1] + red[2] + red[3];
        ws[WS_NORMCLS + c] = sqrtf(t);
    }
}

// ---------------- Phase 0b: class_hvs -> fp16 hi/lo, chunked [k8][col][8] ----------------
__global__ __launch_bounds__(256) void prep_b(const float* __restrict__ cls,
                                              float* __restrict__ ws)
{
    int c = blockIdx.x * 256 + threadIdx.x;
    if (c >= BP_CHUNKS) return;
    int col = c & 127, k8 = c >> 7;
    f16x8 hi, lo;
    #pragma unroll
    for (int j = 0; j < 8; ++j) {
        int k = k8 * 8 + j;
        float v = (col < NCLS && k < DDIM) ? cls[(size_t)col * DDIM + k] : 0.f;
        f16 h = (f16)v;
        hi[j] = h;
        lo[j] = (f16)(v - (float)h);
    }
    ((f16x8*)(ws + WS_BPH))[c] = hi;
    ((f16x8*)(ws + WS_BPL))[c] = lo;
}

// ---------------- Phase 1: MFMA GEMM ----------------
// A: HBM -> per-lane frag regs -> convert (NO LDS). B: prepped hi/lo, regs -> LDS dbuf.
// grid (64, KSPLIT); 4 waves; wave w -> rows [r0+32w, +32) (mt=2 tiles), 112 live cols.
__global__ __launch_bounds__(256, 2) void gemm_mfma(const float* __restrict__ enc,
                                                    float* __restrict__ ws)
{
    __shared__ f16 Bh[2][4*128*8], Bl[2][4*128*8];   // [buf][kg][colS][8], 8KB halves

    int tid = threadIdx.x;
    int w = __builtin_amdgcn_readfirstlane(tid >> 6);
    int l = tid & 63;
    int lane15 = l & 15, lg = l >> 4;
    int r0 = blockIdx.x * BM;
    int ky = blockIdx.y;
    int s_beg = (KS32 * ky) / KSPLIT;
    int s_end = (KS32 * (ky + 1)) / KSPLIT;

    const float* aptr0 = enc + (size_t)(r0 + w * 32 + lane15) * DDIM;
    const float* aptr1 = aptr0 + (size_t)16 * DDIM;
    const f16* bph = (const f16*)(ws + WS_BPH);
    const f16* bpl = (const f16*)(ws + WS_BPL);

    f32x4 acc[2][7] = {};
    float nsq0 = 0.f, nsq1 = 0.f;

    float4 a00, a01, a10, a11;     // A(S) frags: [mt][half], k = S*32 + lg*8 + j
    f16x8 bsh0, bsh1, bsl0, bsl1;  // B(S) stage regs (wave's kg=w share)

    #define LOAD_A(S) do {                                               \
        int k_ = (S) * 32 + lg * 8;                                      \
        int ka_ = (k_ + 4 <= DDIM) ? k_ : 0;                             \
        int kb_ = (k_ + 8 <= DDIM) ? (k_ + 4) : 0;                       \
        a00 = *(const float4*)(aptr0 + ka_);                             \
        a01 = *(const float4*)(aptr0 + kb_);                             \
        a10 = *(const float4*)(aptr1 + ka_);                             \
        a11 = *(const float4*)(aptr1 + kb_);                             \
    } while (0)

    #define LOAD_B(S) do {                                               \
        size_t base_ = ((size_t)((S) * 4 + w) * 128) * 8;                \
        bsh0 = *(const f16x8*)(bph + base_ + (size_t)l * 8);             \
        bsh1 = *(const f16x8*)(bph + base_ + (size_t)(l + 64) * 8);      \
        bsl0 = *(const f16x8*)(bpl + base_ + (size_t)l * 8);             \
        bsl1 = *(const f16x8*)(bpl + base_ + (size_t)(l + 64) * 8);      \
    } while (0)

    LOAD_A(s_beg);
    LOAD_B(s_beg);

    for (int S = s_beg; S < s_end; ++S) {
        int cur = S & 1;

        // 1. convert A(S) regs -> hi/lo frags (+ tail mask + norm accum)
        int kb = S * 32 + lg * 8;
        bool tail = (kb + 8 > DDIM);
        f16x8 ah0, al0, ah1, al1;
        {
            float v[8] = {a00.x, a00.y, a00.z, a00.w, a01.x, a01.y, a01.z, a01.w};
            if (tail) {
                #pragma unroll
                for (int j = 0; j < 8; ++j) if (kb + j >= DDIM) v[j] = 0.f;
            }
            #pragma unroll
            for (int j = 0; j < 8; ++j) {
                f16 h = (f16)v[j];
                ah0[j] = h;
                al0[j] = (f16)(v[j] - (float)h);
                nsq0 = fmaf(v[j], v[j], nsq0);
            }
        }
        {
            float v[8] = {a10.x, a10.y, a10.z, a10.w, a11.x, a11.y, a11.z, a11.w};
            if (tail) {
                #pragma unroll
                for (int j = 0; j < 8; ++j) if (kb + j >= DDIM) v[j] = 0.f;
            }
            #pragma unroll
            for (int j = 0; j < 8; ++j) {
                f16 h = (f16)v[j];
                ah1[j] = h;
                al1[j] = (f16)(v[j] - (float)h);
                nsq1 = fmaf(v[j], v[j], nsq1);
            }
        }

        // 2. ds_write B(S) stage regs -> buf[cur], XOR-swizzled slots
        {
            int sl0 = w * 128 + (l ^ w);
            *(f16x8*)&Bh[cur][sl0 * 8] = bsh0;
            *(f16x8*)&Bh[cur][(sl0 + 64) * 8] = bsh1;
            *(f16x8*)&Bl[cur][sl0 * 8] = bsl0;
            *(f16x8*)&Bl[cur][(sl0 + 64) * 8] = bsl1;
        }

        // 3. prefetch A(S+1), B(S+1) (clamped reload at the end, discarded)
        {
            int Sn = (S + 1 < s_end) ? (S + 1) : S;
            LOAD_A(Sn);
            LOAD_B(Sn);
        }

        // 4. fence: B(S) ds_writes visible to all waves
        SCHED();
        asm volatile("s_waitcnt lgkmcnt(0)" ::: "memory");
        SBAR();
        SCHED();

        // 5. read B frags + 42 MFMA (cols 0..111; nt=7 is padding, skipped)
        #pragma unroll
        for (int nt = 0; nt < 7; ++nt) {
            int colS = (nt * 16 + lane15) ^ lg;
            f16x8 bh = *(const f16x8*)&Bh[cur][(lg * 128 + colS) * 8];
            f16x8 bl = *(const f16x8*)&Bl[cur][(lg * 128 + colS) * 8];
            acc[0][nt] = __builtin_amdgcn_mfma_f32_16x16x32_f16(ah0, bh, acc[0][nt], 0, 0, 0);
            acc[0][nt] = __builtin_amdgcn_mfma_f32_16x16x32_f16(al0, bh, acc[0][nt], 0, 0, 0);
            acc[0][nt] = __builtin_amdgcn_mfma_f32_16x16x32_f16(ah0, bl, acc[0][nt], 0, 0, 0);
            acc[1][nt] = __builtin_amdgcn_mfma_f32_16x16x32_f16(ah1, bh, acc[1][nt], 0, 0, 0);
            acc[1][nt] = __builtin_amdgcn_mfma_f32_16x16x32_f16(al1, bh, acc[1][nt], 0, 0, 0);
            acc[1][nt] = __builtin_amdgcn_mfma_f32_16x16x32_f16(ah1, bl, acc[1][nt], 0, 0, 0);
        }
    }

    // ---- epilogue: partial scores (C layout: col=lane15, row=lg*4+j) ----
    float* scp = ws + WS_SCP + (size_t)ky * SCORES_N;
    #pragma unroll
    for (int mt = 0; mt < 2; ++mt) {
        #pragma unroll
        for (int nt = 0; nt < 7; ++nt) {
            int gcol = nt * 16 + lane15;
            if (gcol < NCLS) {
                #pragma unroll
                for (int j = 0; j < 4; ++j) {
                    int grow = r0 + w * 32 + mt * 16 + lg * 4 + j;
                    scp[(size_t)grow * NCLS + gcol] = acc[mt][nt][j];
                }
            }
        }
    }

    // ---- row-norm partials: reduce across lg (lanes l, l+16, l+32, l+48) ----
    nsq0 += __shfl_xor(nsq0, 16, 64);
    nsq0 += __shfl_xor(nsq0, 32, 64);
    nsq1 += __shfl_xor(nsq1, 16, 64);
    nsq1 += __shfl_xor(nsq1, 32, 64);
    if (l < 16) {
        ws[WS_NRM + (size_t)ky * NROWS + r0 + w * 32 + l] = nsq0;
        ws[WS_NRM + (size_t)ky * NROWS + r0 + w * 32 + 16 + l] = nsq1;
    }
}

// ---------------- Phase 2: finalize scores, argmax, build class lists ----------------
__global__ __launch_bounds__(256) void finalize(const int* __restrict__ targets,
                                                float* __restrict__ out,
                                                float* __restrict__ ws)
{
    int w = threadIdx.x >> 6, l = threadIdx.x & 63;
    int row = blockIdx.x * 4 + w;
    const float* scp = ws + WS_SCP;

    float n2 = 0.f;
    #pragma unroll
    for (int ky = 0; ky < KSPLIT; ++ky) n2 += ws[WS_NRM + (size_t)ky * NROWS + row];
    float ne = sqrtf(n2);

    float best; int bi;
    {
        int c = l;
        float dsum = 0.f;
        #pragma unroll
        for (int ky = 0; ky < KSPLIT; ++ky)
            dsum += scp[(size_t)ky * SCORES_N + (size_t)row * NCLS + c];
        float s = dsum / (ne * ws[WS_NORMCLS + c]);
        out[(size_t)row * NCLS + c] = s;
        best = s; bi = c;
    }
    if (l + 64 < NCLS) {
        int c = l + 64;
        float dsum = 0.f;
        #pragma unroll
        for (int ky = 0; ky < KSPLIT; ++ky)
            dsum += scp[(size_t)ky * SCORES_N + (size_t)row * NCLS + c];
        float s = dsum / (ne * ws[WS_NORMCLS + c]);
        out[(size_t)row * NCLS + c] = s;
        if (s > best) { best = s; bi = c; }   // ties keep smaller index
    }
    #pragma unroll
    for (int off = 32; off; off >>= 1) {
        float ov = __shfl_xor(best, off, 64);
        int   oi = __shfl_xor(bi, off, 64);
        if (ov > best || (ov == best && oi < bi)) { best = ov; bi = oi; }
    }
    if (l == 0) {
        int tgt = targets[row];
        if (tgt != bi) {
            int* wsi = (int*)ws;
            int p1 = atomicAdd(wsi + WS_CNT_T + tgt, 1);
            if (p1 < LISTCAP) wsi[WS_LIST_T + tgt * LISTCAP + p1] = row;
            int p2 = atomicAdd(wsi + WS_CNT_P + bi, 1);
            if (p2 < LISTCAP) wsi[WS_LIST_P + bi * LISTCAP + p2] = row;
        }
    }
}

// ---------------- Phase 3: perceptron update ----------------
// grid (NCLS, 10): class-fast cohort for L3 reuse; lists staged in LDS; unrolled MLP.
__global__ __launch_bounds__(256) void update(const float* __restrict__ enc,
                                              const float* __restrict__ cls,
                                              float* __restrict__ out,
                                              const float* __restrict__ ws)
{
    __shared__ int lstT[LISTCAP], lstP[LISTCAP];
    int c = blockIdx.x;
    const int* wsi = (const int*)ws;
    int nt = wsi[WS_CNT_T + c]; nt = nt < LISTCAP ? nt : LISTCAP;
    int np = wsi[WS_CNT_P + c]; np = np < LISTCAP ? np : LISTCAP;
    for (int i = threadIdx.x; i < nt; i += 256) lstT[i] = wsi[WS_LIST_T + c * LISTCAP + i];
    for (int i = threadIdx.x; i < np; i += 256) lstP[i] = wsi[WS_LIST_P + c * LISTCAP + i];
    __syncthreads();

    int d4 = blockIdx.y * 256 + threadIdx.x;     // float4 index; DDIM/4 = 2500
    if (d4 >= DDIM / 4) return;
    const float4* enc4 = (const float4*)enc;
    const float4* cls4 = (const float4*)cls;

    float4 ac0 = make_float4(0.f, 0.f, 0.f, 0.f);
    float4 ac1 = make_float4(0.f, 0.f, 0.f, 0.f);
    int i = 0;
    #pragma unroll 2
    for (; i + 2 <= nt; i += 2) {
        float4 e0 = enc4[(size_t)lstT[i] * (DDIM / 4) + d4];
        float4 e1 = enc4[(size_t)lstT[i + 1] * (DDIM / 4) + d4];
        ac0.x += e0.x; ac0.y += e0.y; ac0.z += e0.z; ac0.w += e0.w;
        ac1.x += e1.x; ac1.y += e1.y; ac1.z += e1.z; ac1.w += e1.w;
    }
    if (i < nt) {
        float4 e0 = enc4[(size_t)lstT[i] * (DDIM / 4) + d4];
        ac0.x += e0.x; ac0.y += e0.y; ac0.z += e0.z; ac0.w += e0.w;
    }
    i = 0;
    #pragma unroll 2
    for (; i + 2 <= np; i += 2) {
        float4 e0 = enc4[(size_t)lstP[i] * (DDIM / 4) + d4];
        float4 e1 = enc4[(size_t)lstP[i + 1] * (DDIM / 4) + d4];
        ac0.x -= e0.x; ac0.y -= e0.y; ac0.z -= e0.z; ac0.w -= e0.w;
        ac1.x -= e1.x; ac1.y -= e1.y; ac1.z -= e1.z; ac1.w -= e1.w;
    }
    if (i < np) {
        float4 e0 = enc4[(size_t)lstP[i] * (DDIM / 4) + d4];
        ac0.x -= e0.x; ac0.y -= e0.y; ac0.z -= e0.z; ac0.w -= e0.w;
    }

    float4 cv = cls4[(size_t)c * (DDIM / 4) + d4];
    float4 r = make_float4(cv.x + ac0.x + ac1.x, cv.y + ac0.y + ac1.y,
                           cv.z + ac0.z + ac1.z, cv.w + ac0.w + ac1.w);
    ((float4*)out)[SCORES_N / 4 + (size_t)c * (DDIM / 4) + d4] = r;
}

// ---------------- launch ----------------
extern "C" void kernel_launch(void* const* d_in, const int* in_sizes, int n_in,
                              void* d_out, int out_size, void* d_ws, size_t ws_size,
                              hipStream_t stream)
{
    const float* enc = (const float*)d_in[0];
    const float* cls = (const float*)d_in[1];
    const int*   tgt = (const int*)d_in[2];
    float* out = (float*)d_out;
    float* ws  = (float*)d_ws;

    cls_norms<<<NCLS, 256, 0, stream>>>(cls, ws);
    prep_b<<<(BP_CHUNKS + 255) / 256, 256, 0, stream>>>(cls, ws);

    dim3 g1(NROWS / BM, KSPLIT);
    gemm_mfma<<<g1, 256, 0, stream>>>(enc, ws);

    finalize<<<NROWS / 4, 256, 0, stream>>>(tgt, out, ws);

    dim3 g3(NCLS, (DDIM / 4 + 255) / 256);
    update<<<g3, 256, 0, stream>>>(enc, cls, out, ws);
}